// Round 1
// baseline (900.532 us; speedup 1.0000x reference)
//
#include <hip/hip_runtime.h>

// ---------------------------------------------------------------------------
// Fused CNF ODE func: f = MLP(z,ctx,t), neg_div = -eps^T (d/dz)(f . eps)
// B=500000, DIM=3, COND=64, IN=68, HID=128.
//
// Strategy: f16 MFMA (16x16x32) fused fwd+vjp. Weights pre-converted to f16
// in d_ws by a prep kernel (both orientations: fwd wants [n][k], bwd wants
// [a][b]). Main kernel: 512 thr (8 waves), 48-row tiles, wave w owns N-slice
// [16w,16w+16). h1/h2/h3 kept in C-fragment registers for tanh-grads; LDS
// holds weights + two 48x132 activation ping-pong buffers (152.3 KB dynamic).
// ---------------------------------------------------------------------------

#define B_N   500000
#define NT    10417          // ceil(500000/48)

// ws layout (f16 element offsets)
#define OFF_WFIN   0         // [128][100]  fwd W_in^T  (k: 0..63 ctx, 64..66 z, 67 t, pad 0)
#define OFF_WF1    12800     // [128][132]  fwd W_h1^T
#define OFF_WF2    29696     // [128][132]  fwd W_h2^T
#define OFF_WB2    46592     // [128][132]  bwd W_h2 (original [a][b])
#define OFF_WB1    63488     // [128][128]  bwd W_h1 (original, read from L2)
#define OFF_WFOUT  79872     // [16][128]   fwd W_out^T rows 0..2 (read from L2)
#define OFF_WBOUT  81920     // [128][32]   bwd W_out  (k=0..2 real, read from L2)
#define OFF_WBZ    86016     // [16][128]   bwd W_in rows 0..2 (read from L2)
#define WS_TOTAL   88064     // f16 elements -> 176128 bytes

#define LDS_F16    76160     // 63488 weights + 2*6336 buffers
#define LDS_BYTES  (LDS_F16*2)

typedef _Float16 f16x8 __attribute__((ext_vector_type(8)));
typedef float    f32x4 __attribute__((ext_vector_type(4)));

union F8 { f16x8 v; _Float16 e[8]; uint2 d2[2]; uint4 d4; };

static __device__ inline f16x8 lds_ld8(const _Float16* p) {
    F8 f;
    f.d2[0] = *reinterpret_cast<const uint2*>(p);
    f.d2[1] = *reinterpret_cast<const uint2*>(p + 4);
    return f.v;
}
static __device__ inline f16x8 g_ld8(const _Float16* p) {
    F8 f;
    f.d4 = *reinterpret_cast<const uint4*>(p);
    return f.v;
}
static __device__ inline f32x4 mfma16(f16x8 a, f16x8 b, f32x4 c) {
    return __builtin_amdgcn_mfma_f32_16x16x32_f16(a, b, c, 0, 0, 0);
}

// ---------------------------------------------------------------------------
// Prep: fp32 weights -> f16 ws arrays (transposed / padded / zero-filled)
// ---------------------------------------------------------------------------
__global__ void prep_kernel(const float* __restrict__ W_in,
                            const float* __restrict__ W_h1,
                            const float* __restrict__ W_h2,
                            const float* __restrict__ W_out,
                            _Float16* __restrict__ ws) {
    int i = blockIdx.x * 256 + threadIdx.x;
    if (i >= WS_TOTAL) return;
    float v = 0.f;
    if (i < OFF_WF1) {                       // fwd W_in^T [n][100]
        int n = i / 100, k = i - n * 100;
        if      (k < 64) v = W_in[(3 + k) * 128 + n];     // ctx part (orig rows 3..66)
        else if (k < 67) v = W_in[(k - 64) * 128 + n];    // z part (orig rows 0..2)
        else if (k == 67) v = W_in[67 * 128 + n];         // t feature (orig row 67)
    } else if (i < OFF_WF2) {                // fwd W_h1^T [n][132]
        int j = i - OFF_WF1; int n = j / 132, k = j - n * 132;
        if (k < 128) v = W_h1[k * 128 + n];
    } else if (i < OFF_WB2) {                // fwd W_h2^T [n][132]
        int j = i - OFF_WF2; int n = j / 132, k = j - n * 132;
        if (k < 128) v = W_h2[k * 128 + n];
    } else if (i < OFF_WB1) {                // bwd W_h2 original [a][132]
        int j = i - OFF_WB2; int a = j / 132, b = j - a * 132;
        if (b < 128) v = W_h2[a * 128 + b];
    } else if (i < OFF_WFOUT) {              // bwd W_h1 original [a][128]
        int j = i - OFF_WB1;
        v = W_h1[j];
    } else if (i < OFF_WBOUT) {              // fwd W_out^T [n'][128], rows>=3 zero
        int j = i - OFF_WFOUT; int n = j >> 7, b = j & 127;
        if (n < 3) v = W_out[b * 3 + n];
    } else if (i < OFF_WBZ) {                // bwd W_out [b][32], k>=3 zero
        int j = i - OFF_WBOUT; int b = j >> 5, k = j & 31;
        if (k < 3) v = W_out[b * 3 + k];
    } else {                                 // bwd W_in rows 0..2 [n'][128]
        int j = i - OFF_WBZ; int n = j >> 7, a = j & 127;
        if (n < 3) v = W_in[n * 128 + a];
    }
    ws[i] = (_Float16)v;
}

// ---------------------------------------------------------------------------
// Main fused kernel
// ---------------------------------------------------------------------------
__global__ __launch_bounds__(512, 2) void fused_kernel(
        const float* __restrict__ t_p,  const float* __restrict__ z,
        const float* __restrict__ ctx,  const float* __restrict__ eps,
        const float* __restrict__ b_in, const float* __restrict__ b_h1,
        const float* __restrict__ b_h2, const float* __restrict__ b_out,
        const float* __restrict__ os_p, const _Float16* __restrict__ ws,
        float* __restrict__ out) {
    extern __shared__ _Float16 smem[];
    _Float16* WFIN = smem + OFF_WFIN;
    _Float16* WF1  = smem + OFF_WF1;
    _Float16* WF2  = smem + OFF_WF2;
    _Float16* WB2  = smem + OFF_WB2;
    _Float16* BUF0 = smem + 63488;           // [48][132]
    _Float16* BUF1 = smem + 69824;           // [48][132]

    const _Float16* WB1g   = ws + OFF_WB1;
    const _Float16* WFOUTg = ws + OFF_WFOUT;
    const _Float16* WBOUTg = ws + OFF_WBOUT;
    const _Float16* WBZg   = ws + OFF_WBZ;

    const int tid  = threadIdx.x;
    const int wave = tid >> 6;
    const int lane = tid & 63;
    const int l15  = lane & 15;
    const int q    = lane >> 4;
    const int ng   = (wave << 4) + l15;      // this wave's N-column (0..127)

    // stage resident weights ws -> LDS (flat copy of first 63488 f16)
    {
        const uint4* src = reinterpret_cast<const uint4*>(ws);
        uint4* dst = reinterpret_cast<uint4*>(smem);
        for (int i = tid; i < 7936; i += 512) dst[i] = src[i];
    }

    const float tval  = t_p[0];
    const float os    = os_p[0];
    const float bin_v = b_in[ng];
    const float b1_v  = b_h1[ng];
    const float b2_v  = b_h2[ng];
    const float bo_v  = (l15 < 3) ? b_out[l15] : 0.f;
    float* out_f  = out;
    float* out_nd = out + (size_t)B_N * 3;

    __syncthreads();

    const f32x4 zero4 = {0.f, 0.f, 0.f, 0.f};

    for (int tile = blockIdx.x; tile < NT; tile += gridDim.x) {
        const int base = tile * 48;
        __syncthreads();                                     // A

        // ---- stage input tile -> BUF0  cols: [ctx(64) | z(3) | t | zeros..99]
        for (int i2 = tid; i2 < 4800; i2 += 512) {
            int row = i2 / 100, col = i2 - row * 100;
            int r = base + row;
            float v = 0.f;
            if (col < 64)      { if (r < B_N) v = ctx[(size_t)r * 64 + col]; }
            else if (col < 67) { if (r < B_N) v = z[(size_t)r * 3 + (col - 64)]; }
            else if (col == 67) v = tval;
            BUF0[row * 132 + col] = (_Float16)v;
        }
        __syncthreads();                                     // B

        // ---- L1: x1 = inp @ W_in  (K=96 incl. pad), A=BUF0, B=WFIN
        f32x4 acc[3]; acc[0] = acc[1] = acc[2] = zero4;
        for (int k0 = 0; k0 < 96; k0 += 32) {
            f16x8 bv = lds_ld8(WFIN + ng * 100 + k0 + q * 8);
            #pragma unroll
            for (int m = 0; m < 3; ++m) {
                f16x8 av = lds_ld8(BUF0 + (m * 16 + l15) * 132 + k0 + q * 8);
                acc[m] = mfma16(av, bv, acc[m]);
            }
        }
        float h1r[3][4];
        #pragma unroll
        for (int m = 0; m < 3; ++m)
            #pragma unroll
            for (int i = 0; i < 4; ++i) {
                float h = tanhf(acc[m][i] + bin_v);
                h1r[m][i] = h;
                BUF1[(m * 16 + q * 4 + i) * 132 + ng] = (_Float16)h;
            }
        __syncthreads();                                     // C

        // ---- L2: h2 = tanh(h1 @ W_h1 + b)  A=BUF1, B=WF1
        acc[0] = acc[1] = acc[2] = zero4;
        for (int k0 = 0; k0 < 128; k0 += 32) {
            f16x8 bv = lds_ld8(WF1 + ng * 132 + k0 + q * 8);
            #pragma unroll
            for (int m = 0; m < 3; ++m) {
                f16x8 av = lds_ld8(BUF1 + (m * 16 + l15) * 132 + k0 + q * 8);
                acc[m] = mfma16(av, bv, acc[m]);
            }
        }
        float h2r[3][4];
        #pragma unroll
        for (int m = 0; m < 3; ++m)
            #pragma unroll
            for (int i = 0; i < 4; ++i) {
                float h = tanhf(acc[m][i] + b1_v);
                h2r[m][i] = h;
                BUF0[(m * 16 + q * 4 + i) * 132 + ng] = (_Float16)h;
            }
        __syncthreads();                                     // D

        // ---- u3pre = eps @ W_out^T  (K=32, only k<3 real)  B from L2(ws)
        f32x4 up[3];
        #pragma unroll
        for (int m = 0; m < 3; ++m) {
            F8 ae; ae.d4 = make_uint4(0u, 0u, 0u, 0u);
            if (q == 0) {
                int r = base + m * 16 + l15;
                if (r < B_N) {
                    ae.e[0] = (_Float16)eps[(size_t)r * 3 + 0];
                    ae.e[1] = (_Float16)eps[(size_t)r * 3 + 1];
                    ae.e[2] = (_Float16)eps[(size_t)r * 3 + 2];
                }
            }
            f16x8 bv = g_ld8(WBOUTg + ng * 32 + q * 8);
            up[m] = mfma16(ae.v, bv, zero4);
        }

        // ---- L3: h3 = tanh(h2 @ W_h2 + b); u3 = os*u3pre*(1-h3^2) -> BUF1
        acc[0] = acc[1] = acc[2] = zero4;
        for (int k0 = 0; k0 < 128; k0 += 32) {
            f16x8 bv = lds_ld8(WF2 + ng * 132 + k0 + q * 8);
            #pragma unroll
            for (int m = 0; m < 3; ++m) {
                f16x8 av = lds_ld8(BUF0 + (m * 16 + l15) * 132 + k0 + q * 8);
                acc[m] = mfma16(av, bv, acc[m]);
            }
        }
        float h3r[3][4];
        #pragma unroll
        for (int m = 0; m < 3; ++m)
            #pragma unroll
            for (int i = 0; i < 4; ++i) {
                float h = tanhf(acc[m][i] + b2_v);
                h3r[m][i] = h;
                float u3 = os * up[m][i] * (1.f - h * h);
                BUF1[(m * 16 + q * 4 + i) * 132 + ng] = (_Float16)u3;
            }
        __syncthreads();                                     // E

        // ---- stage h3 -> BUF0 (for wave0's f GEMM); bwd3: u2pre = u3 @ W_h2^T
        #pragma unroll
        for (int m = 0; m < 3; ++m)
            #pragma unroll
            for (int i = 0; i < 4; ++i)
                BUF0[(m * 16 + q * 4 + i) * 132 + ng] = (_Float16)h3r[m][i];

        acc[0] = acc[1] = acc[2] = zero4;
        for (int k0 = 0; k0 < 128; k0 += 32) {
            f16x8 bv = lds_ld8(WB2 + ng * 132 + k0 + q * 8);
            #pragma unroll
            for (int m = 0; m < 3; ++m) {
                f16x8 av = lds_ld8(BUF1 + (m * 16 + l15) * 132 + k0 + q * 8);
                acc[m] = mfma16(av, bv, acc[m]);
            }
        }
        float u2r[3][4];
        #pragma unroll
        for (int m = 0; m < 3; ++m)
            #pragma unroll
            for (int i = 0; i < 4; ++i)
                u2r[m][i] = acc[m][i] * (1.f - h2r[m][i] * h2r[m][i]);
        __syncthreads();                                     // F

        // ---- wave0: f = (h3 @ W_out + b_out)*os ; all: write u2 -> BUF1
        if (wave == 0) {
            f32x4 fa[3]; fa[0] = fa[1] = fa[2] = zero4;
            for (int k0 = 0; k0 < 128; k0 += 32) {
                f16x8 bv = g_ld8(WFOUTg + l15 * 128 + k0 + q * 8);
                #pragma unroll
                for (int m = 0; m < 3; ++m) {
                    f16x8 av = lds_ld8(BUF0 + (m * 16 + l15) * 132 + k0 + q * 8);
                    fa[m] = mfma16(av, bv, fa[m]);
                }
            }
            #pragma unroll
            for (int m = 0; m < 3; ++m)
                #pragma unroll
                for (int i = 0; i < 4; ++i) {
                    int r = base + m * 16 + q * 4 + i;
                    if (l15 < 3 && r < B_N)
                        out_f[(size_t)r * 3 + l15] = (fa[m][i] + bo_v) * os;
                }
        }
        #pragma unroll
        for (int m = 0; m < 3; ++m)
            #pragma unroll
            for (int i = 0; i < 4; ++i)
                BUF1[(m * 16 + q * 4 + i) * 132 + ng] = (_Float16)u2r[m][i];
        __syncthreads();                                     // G

        // ---- bwd2: u1 = (u2 @ W_h1^T)*(1-h1^2) -> BUF0   (B frags from L2)
        acc[0] = acc[1] = acc[2] = zero4;
        for (int k0 = 0; k0 < 128; k0 += 32) {
            f16x8 bv = g_ld8(WB1g + ng * 128 + k0 + q * 8);
            #pragma unroll
            for (int m = 0; m < 3; ++m) {
                f16x8 av = lds_ld8(BUF1 + (m * 16 + l15) * 132 + k0 + q * 8);
                acc[m] = mfma16(av, bv, acc[m]);
            }
        }
        #pragma unroll
        for (int m = 0; m < 3; ++m)
            #pragma unroll
            for (int i = 0; i < 4; ++i)
                BUF0[(m * 16 + q * 4 + i) * 132 + ng] =
                    (_Float16)(acc[m][i] * (1.f - h1r[m][i] * h1r[m][i]));
        __syncthreads();                                     // H

        // ---- wave0: gz = u1 @ W_in[:3]^T ; neg_div = -sum(gz*eps)
        if (wave == 0) {
            f32x4 g[3]; g[0] = g[1] = g[2] = zero4;
            for (int k0 = 0; k0 < 128; k0 += 32) {
                f16x8 bv = g_ld8(WBZg + l15 * 128 + k0 + q * 8);
                #pragma unroll
                for (int m = 0; m < 3; ++m) {
                    f16x8 av = lds_ld8(BUF0 + (m * 16 + l15) * 132 + k0 + q * 8);
                    g[m] = mfma16(av, bv, g[m]);
                }
            }
            #pragma unroll
            for (int m = 0; m < 3; ++m)
                #pragma unroll
                for (int i = 0; i < 4; ++i) {
                    int r = base + m * 16 + q * 4 + i;
                    float ev = (l15 < 3 && r < B_N) ? eps[(size_t)r * 3 + l15] : 0.f;
                    float p  = g[m][i] * ev;
                    float p1 = __shfl_down(p, 1);
                    float p2 = __shfl_down(p, 2);
                    if (l15 == 0 && r < B_N) out_nd[r] = -(p + p1 + p2);
                }
        }
        // loop-top sync (A) separates gz reads / next staging writes
    }
}

extern "C" void kernel_launch(void* const* d_in, const int* in_sizes, int n_in,
                              void* d_out, int out_size, void* d_ws, size_t ws_size,
                              hipStream_t stream) {
    const float* t_p   = (const float*)d_in[0];
    const float* z     = (const float*)d_in[1];
    // d_in[2] = logp (unused by reference outputs)
    const float* ctx   = (const float*)d_in[3];
    const float* eps   = (const float*)d_in[4];
    const float* W_in  = (const float*)d_in[5];
    const float* b_in  = (const float*)d_in[6];
    const float* W_h1  = (const float*)d_in[7];
    const float* b_h1  = (const float*)d_in[8];
    const float* W_h2  = (const float*)d_in[9];
    const float* b_h2  = (const float*)d_in[10];
    const float* W_out = (const float*)d_in[11];
    const float* b_out = (const float*)d_in[12];
    const float* os_p  = (const float*)d_in[13];
    _Float16* ws = (_Float16*)d_ws;
    float* out = (float*)d_out;

    static bool attr_set = false;  // idempotent host-side attribute (not a stream op)
    if (!attr_set) {
        (void)hipFuncSetAttribute((const void*)fused_kernel,
                                  hipFuncAttributeMaxDynamicSharedMemorySize,
                                  LDS_BYTES);
        attr_set = true;
    }

    prep_kernel<<<344, 256, 0, stream>>>(W_in, W_h1, W_h2, W_out, ws);
    fused_kernel<<<256, 512, LDS_BYTES, stream>>>(
        t_p, z, ctx, eps, b_in, b_h1, b_h2, b_out, os_p, ws, out);
}

// Round 2
// 632.350 us; speedup vs baseline: 1.4241x; 1.4241x over previous
//
#include <hip/hip_runtime.h>

// ---------------------------------------------------------------------------
// Fused CNF ODE func: f = MLP(z,ctx,t), neg_div = -eps^T d(f.eps)/dz
// B=500000, DIM=3, COND=64, IN=68, HID=128.
//
// Round 2: per-wave-independent tiles (16 rows/wave), ZERO inner barriers.
// Each wave: stage inputs -> L1 -> L2 -> u3pre -> L3 -> f -> bwd3 -> bwd2 ->
// gz, using a private 16x132 LDS scratch for C->A layout transforms
// (within-wave LDS round trip, in-order DS pipeline, no __syncthreads).
// Weights: fwd W^T + W_out frags in LDS (block-shared); bwd W_h1/W_h2/W_out
// read from L2 (64KB hot set). 500000 = 16*31250 exactly -> no row guards.
// ---------------------------------------------------------------------------

#define B_N     500000
#define NTILES  31250          // 16-row tiles, exact
#define GRID    256
#define NSTREAM (GRID * 8)     // independent wave streams

// ws f16-element offsets
#define OFF_WFIN   0           // [128][100] fwd W_in^T (k:0..63 ctx,64..66 z,67 t)
#define OFF_WF1    12800       // [128][132] fwd W_h1^T
#define OFF_WF2    29696       // [128][132] fwd W_h2^T
#define OFF_WFOUT  46592       // [16][132]  f-GEMM B: row n = W_out[:,n] (n<3 real)
#define OFF_WBZ    48704       // [16][132]  gz B: row n = W_in[n,:] (n<3 real)
#define LDS_W      50816       // elements copied to LDS
#define OFF_WBOUT  50816       // [128][32]  u3pre B: row n = W_out[n,:] pad (L2)
#define OFF_WB1    54912       // [128][128] bwd W_h1 original (L2)
#define OFF_WB2    71296       // [128][128] bwd W_h2 original (L2)
#define WS_TOTAL   87680       // f16 elements -> 175360 bytes

#define BUF_ELEMS  2112        // 16x132 per-wave scratch
#define LDS_ELEMS  (LDS_W + 8 * BUF_ELEMS)   // 67712 -> 135424 B
#define LDS_BYTES  (LDS_ELEMS * 2)

typedef _Float16 f16x8 __attribute__((ext_vector_type(8)));
typedef float    f32x4 __attribute__((ext_vector_type(4)));

union F8 { f16x8 v; _Float16 e[8]; uint2 d2[2]; uint4 d4; };

static __device__ inline f16x8 lds_ld8(const _Float16* p) {
    F8 f;
    f.d2[0] = *reinterpret_cast<const uint2*>(p);
    f.d2[1] = *reinterpret_cast<const uint2*>(p + 4);
    return f.v;
}
static __device__ inline f16x8 g_ld8(const _Float16* p) {
    F8 f;
    f.d4 = *reinterpret_cast<const uint4*>(p);
    return f.v;
}
static __device__ inline f32x4 mfma16(f16x8 a, f16x8 b, f32x4 c) {
    return __builtin_amdgcn_mfma_f32_16x16x32_f16(a, b, c, 0, 0, 0);
}
static __device__ inline float ftanh(float x) {
    // tanh(x) = 1 - 2/(exp(2x)+1); exact at +/-inf, ~1e-6 rel err
    float e = __expf(2.f * x);
    return 1.f - 2.f * __builtin_amdgcn_rcpf(e + 1.f);
}

// ---------------------------------------------------------------------------
// Prep: fp32 weights -> f16 ws arrays
// ---------------------------------------------------------------------------
__global__ void prep_kernel(const float* __restrict__ W_in,
                            const float* __restrict__ W_h1,
                            const float* __restrict__ W_h2,
                            const float* __restrict__ W_out,
                            _Float16* __restrict__ ws) {
    int i = blockIdx.x * 256 + threadIdx.x;
    if (i >= WS_TOTAL) return;
    float v = 0.f;
    if (i < OFF_WF1) {                        // W_in^T [n][100]
        int n = i / 100, k = i - n * 100;
        if      (k < 64)  v = W_in[(3 + k) * 128 + n];
        else if (k < 67)  v = W_in[(k - 64) * 128 + n];
        else if (k == 67) v = W_in[67 * 128 + n];
    } else if (i < OFF_WF2) {                 // W_h1^T [n][132]
        int j = i - OFF_WF1; int n = j / 132, k = j - n * 132;
        if (k < 128) v = W_h1[k * 128 + n];
    } else if (i < OFF_WFOUT) {               // W_h2^T [n][132]
        int j = i - OFF_WF2; int n = j / 132, k = j - n * 132;
        if (k < 128) v = W_h2[k * 128 + n];
    } else if (i < OFF_WBZ) {                 // f-GEMM B [16][132]
        int j = i - OFF_WFOUT; int n = j / 132, k = j - n * 132;
        if (n < 3 && k < 128) v = W_out[k * 3 + n];
    } else if (i < OFF_WBOUT) {               // gz B [16][132]
        int j = i - OFF_WBZ; int n = j / 132, k = j - n * 132;
        if (n < 3 && k < 128) v = W_in[n * 128 + k];
    } else if (i < OFF_WB1) {                 // u3pre B [128][32]
        int j = i - OFF_WBOUT; int n = j >> 5, k = j & 31;
        if (k < 3) v = W_out[n * 3 + k];
    } else if (i < OFF_WB2) {                 // bwd W_h1 [128][128]
        v = W_h1[i - OFF_WB1];
    } else {                                  // bwd W_h2 [128][128]
        v = W_h2[i - OFF_WB2];
    }
    ws[i] = (_Float16)v;
}

// ---------------------------------------------------------------------------
// Main fused kernel — one 16-row tile per wave, no inner barriers
// ---------------------------------------------------------------------------
__global__ __launch_bounds__(512, 2) void fused_kernel(
        const float* __restrict__ t_p,  const float* __restrict__ z,
        const float* __restrict__ ctx,  const float* __restrict__ eps,
        const float* __restrict__ b_in, const float* __restrict__ b_h1,
        const float* __restrict__ b_h2, const float* __restrict__ b_out,
        const float* __restrict__ os_p, const _Float16* __restrict__ ws,
        float* __restrict__ out) {
    extern __shared__ _Float16 smem[];
    const int tid  = threadIdx.x;
    const int wave = tid >> 6;
    const int lane = tid & 63;
    const int l15  = lane & 15;
    const int q    = lane >> 4;

    // stage block-shared weights ws[0..LDS_W) -> LDS
    {
        const uint4* src = reinterpret_cast<const uint4*>(ws);
        uint4* dst = reinterpret_cast<uint4*>(smem);
        for (int i = tid; i < LDS_W / 8; i += 512) dst[i] = src[i];
    }
    __syncthreads();   // the only block barrier

    const _Float16* WFIN  = smem + OFF_WFIN;
    const _Float16* WF1   = smem + OFF_WF1;
    const _Float16* WF2   = smem + OFF_WF2;
    const _Float16* WFOUT = smem + OFF_WFOUT;
    const _Float16* WBZ   = smem + OFF_WBZ;
    _Float16* WBUF = smem + LDS_W + wave * BUF_ELEMS;

    const _Float16* WBOUTg = ws + OFF_WBOUT;
    const _Float16* WB1g   = ws + OFF_WB1;
    const _Float16* WB2g   = ws + OFF_WB2;

    float bin[8], b1v[8], b2v[8];
    #pragma unroll
    for (int n = 0; n < 8; ++n) {
        bin[n] = b_in[n * 16 + l15];
        b1v[n] = b_h1[n * 16 + l15];
        b2v[n] = b_h2[n * 16 + l15];
    }
    const float tval = t_p[0];
    const float os   = os_p[0];
    const float bo   = (l15 < 3) ? b_out[l15] : 0.f;
    float* out_f  = out;
    float* out_nd = out + (size_t)B_N * 3;

    const int row16 = lane >> 2;   // staging: 4 lanes per row
    const int part  = lane & 3;

    const f32x4 zero4 = {0.f, 0.f, 0.f, 0.f};

    for (int tile = blockIdx.x * 8 + wave; tile < NTILES; tile += NSTREAM) {
        const int base = tile * 16;

        // ---- stage inputs: WBUF cols [ctx 0..63 | z 64..66 | t 67 | 0..95]
        {
            const float4* cp = reinterpret_cast<const float4*>(
                ctx + (size_t)(base + row16) * 64 + part * 16);
            float4 c0 = cp[0], c1 = cp[1], c2 = cp[2], c3 = cp[3];
            F8 u0, u1;
            u0.e[0] = (_Float16)c0.x; u0.e[1] = (_Float16)c0.y;
            u0.e[2] = (_Float16)c0.z; u0.e[3] = (_Float16)c0.w;
            u0.e[4] = (_Float16)c1.x; u0.e[5] = (_Float16)c1.y;
            u0.e[6] = (_Float16)c1.z; u0.e[7] = (_Float16)c1.w;
            u1.e[0] = (_Float16)c2.x; u1.e[1] = (_Float16)c2.y;
            u1.e[2] = (_Float16)c2.z; u1.e[3] = (_Float16)c2.w;
            u1.e[4] = (_Float16)c3.x; u1.e[5] = (_Float16)c3.y;
            u1.e[6] = (_Float16)c3.z; u1.e[7] = (_Float16)c3.w;
            _Float16* w = WBUF + row16 * 132 + part * 16;
            *reinterpret_cast<uint2*>(w)      = u0.d2[0];
            *reinterpret_cast<uint2*>(w + 4)  = u0.d2[1];
            *reinterpret_cast<uint2*>(w + 8)  = u1.d2[0];
            *reinterpret_cast<uint2*>(w + 12) = u1.d2[1];
            F8 ex; ex.d4 = make_uint4(0u, 0u, 0u, 0u);
            if (part == 0) {
                const float* zp = z + (size_t)(base + row16) * 3;
                ex.e[0] = (_Float16)zp[0]; ex.e[1] = (_Float16)zp[1];
                ex.e[2] = (_Float16)zp[2]; ex.e[3] = (_Float16)tval;
            }
            _Float16* w2 = WBUF + row16 * 132 + 64 + part * 8;
            *reinterpret_cast<uint2*>(w2)     = ex.d2[0];
            *reinterpret_cast<uint2*>(w2 + 4) = ex.d2[1];
        }
        // eps fragments (A-layout for u3pre; C-layout for final dot)
        F8 ae; ae.d4 = make_uint4(0u, 0u, 0u, 0u);
        if (q == 0) {
            const float* ep = eps + (size_t)(base + l15) * 3;
            ae.e[0] = (_Float16)ep[0]; ae.e[1] = (_Float16)ep[1];
            ae.e[2] = (_Float16)ep[2];
        }
        float ec[4];
        #pragma unroll
        for (int i = 0; i < 4; ++i)
            ec[i] = (l15 < 3) ? eps[(size_t)(base + q * 4 + i) * 3 + l15] : 0.f;

        __builtin_amdgcn_wave_barrier();

        // ---- L1: x1 = inp @ W_in   (K=96 incl pad)
        f32x4 acc[8];
        #pragma unroll
        for (int n = 0; n < 8; ++n) acc[n] = zero4;
        #pragma unroll
        for (int kk = 0; kk < 3; ++kk) {
            f16x8 af = lds_ld8(WBUF + l15 * 132 + kk * 32 + q * 8);
            #pragma unroll
            for (int n = 0; n < 8; ++n) {
                f16x8 bv = lds_ld8(WFIN + (n * 16 + l15) * 100 + kk * 32 + q * 8);
                acc[n] = mfma16(af, bv, acc[n]);
            }
        }
        float h1s[8][4];
        #pragma unroll
        for (int n = 0; n < 8; ++n)
            #pragma unroll
            for (int i = 0; i < 4; ++i) {
                float h = ftanh(acc[n][i] + bin[n]);
                h1s[n][i] = h;
                WBUF[(q * 4 + i) * 132 + n * 16 + l15] = (_Float16)h;
            }
        __builtin_amdgcn_wave_barrier();

        // ---- L2: h2 = tanh(h1 @ W_h1 + b1)
        #pragma unroll
        for (int n = 0; n < 8; ++n) acc[n] = zero4;
        #pragma unroll
        for (int kk = 0; kk < 4; ++kk) {
            f16x8 af = lds_ld8(WBUF + l15 * 132 + kk * 32 + q * 8);
            #pragma unroll
            for (int n = 0; n < 8; ++n) {
                f16x8 bv = lds_ld8(WF1 + (n * 16 + l15) * 132 + kk * 32 + q * 8);
                acc[n] = mfma16(af, bv, acc[n]);
            }
        }
        float h2s[8][4];
        #pragma unroll
        for (int n = 0; n < 8; ++n)
            #pragma unroll
            for (int i = 0; i < 4; ++i) {
                float h = ftanh(acc[n][i] + b1v[n]);
                h2s[n][i] = h;
                WBUF[(q * 4 + i) * 132 + n * 16 + l15] = (_Float16)h;
            }
        __builtin_amdgcn_wave_barrier();

        // ---- u3pre = eps @ W_out^T  (B from L2; latency hidden by L3 MFMAs)
        f32x4 up[8];
        #pragma unroll
        for (int n = 0; n < 8; ++n) {
            f16x8 bv = g_ld8(WBOUTg + (n * 16 + l15) * 32 + q * 8);
            up[n] = mfma16(ae.v, bv, zero4);
        }

        // ---- L3: h3 = tanh(h2 @ W_h2 + b2)
        #pragma unroll
        for (int n = 0; n < 8; ++n) acc[n] = zero4;
        #pragma unroll
        for (int kk = 0; kk < 4; ++kk) {
            f16x8 af = lds_ld8(WBUF + l15 * 132 + kk * 32 + q * 8);
            #pragma unroll
            for (int n = 0; n < 8; ++n) {
                f16x8 bv = lds_ld8(WF2 + (n * 16 + l15) * 132 + kk * 32 + q * 8);
                acc[n] = mfma16(af, bv, acc[n]);
            }
        }
        float h3s[8][4];
        #pragma unroll
        for (int n = 0; n < 8; ++n)
            #pragma unroll
            for (int i = 0; i < 4; ++i) {
                float h = ftanh(acc[n][i] + b2v[n]);
                h3s[n][i] = h;
                WBUF[(q * 4 + i) * 132 + n * 16 + l15] = (_Float16)h;
            }
        __builtin_amdgcn_wave_barrier();

        // ---- f = (h3 @ W_out + b_out) * os   (1 N-tile, cols<3 real)
        {
            f32x4 fa = zero4;
            #pragma unroll
            for (int kk = 0; kk < 4; ++kk) {
                f16x8 af = lds_ld8(WBUF + l15 * 132 + kk * 32 + q * 8);
                f16x8 bv = lds_ld8(WFOUT + l15 * 132 + kk * 32 + q * 8);
                fa = mfma16(af, bv, fa);
            }
            if (l15 < 3) {
                #pragma unroll
                for (int i = 0; i < 4; ++i)
                    out_f[(size_t)(base + q * 4 + i) * 3 + l15] =
                        (fa[i] + bo) * os;
            }
        }
        __builtin_amdgcn_wave_barrier();

        // ---- u3 = os * u3pre * (1 - h3^2) -> WBUF (overwrites h3)
        #pragma unroll
        for (int n = 0; n < 8; ++n)
            #pragma unroll
            for (int i = 0; i < 4; ++i) {
                float u3 = os * up[n][i] * (1.f - h3s[n][i] * h3s[n][i]);
                WBUF[(q * 4 + i) * 132 + n * 16 + l15] = (_Float16)u3;
            }
        __builtin_amdgcn_wave_barrier();

        // ---- bwd3: u2 = (u3 @ W_h2^T) * (1 - h2^2)   (B from L2)
        #pragma unroll
        for (int n = 0; n < 8; ++n) acc[n] = zero4;
        #pragma unroll
        for (int kk = 0; kk < 4; ++kk) {
            f16x8 af = lds_ld8(WBUF + l15 * 132 + kk * 32 + q * 8);
            #pragma unroll
            for (int n = 0; n < 8; ++n) {
                f16x8 bv = g_ld8(WB2g + (n * 16 + l15) * 128 + kk * 32 + q * 8);
                acc[n] = mfma16(af, bv, acc[n]);
            }
        }
        #pragma unroll
        for (int n = 0; n < 8; ++n)
            #pragma unroll
            for (int i = 0; i < 4; ++i) {
                float u2 = acc[n][i] * (1.f - h2s[n][i] * h2s[n][i]);
                WBUF[(q * 4 + i) * 132 + n * 16 + l15] = (_Float16)u2;
            }
        __builtin_amdgcn_wave_barrier();

        // ---- bwd2: u1 = (u2 @ W_h1^T) * (1 - h1^2)   (B from L2)
        #pragma unroll
        for (int n = 0; n < 8; ++n) acc[n] = zero4;
        #pragma unroll
        for (int kk = 0; kk < 4; ++kk) {
            f16x8 af = lds_ld8(WBUF + l15 * 132 + kk * 32 + q * 8);
            #pragma unroll
            for (int n = 0; n < 8; ++n) {
                f16x8 bv = g_ld8(WB1g + (n * 16 + l15) * 128 + kk * 32 + q * 8);
                acc[n] = mfma16(af, bv, acc[n]);
            }
        }
        #pragma unroll
        for (int n = 0; n < 8; ++n)
            #pragma unroll
            for (int i = 0; i < 4; ++i) {
                float u1 = acc[n][i] * (1.f - h1s[n][i] * h1s[n][i]);
                WBUF[(q * 4 + i) * 132 + n * 16 + l15] = (_Float16)u1;
            }
        __builtin_amdgcn_wave_barrier();

        // ---- gz = u1 @ W_in[:3]^T ; neg_div = -sum(gz * eps)
        {
            f32x4 g = zero4;
            #pragma unroll
            for (int kk = 0; kk < 4; ++kk) {
                f16x8 af = lds_ld8(WBUF + l15 * 132 + kk * 32 + q * 8);
                f16x8 bv = lds_ld8(WBZ + l15 * 132 + kk * 32 + q * 8);
                g = mfma16(af, bv, g);
            }
            #pragma unroll
            for (int i = 0; i < 4; ++i) {
                float p  = g[i] * ec[i];
                float p1 = __shfl_down(p, 1);
                float p2 = __shfl_down(p, 2);
                if (l15 == 0) out_nd[base + q * 4 + i] = -(p + p1 + p2);
            }
        }
        __builtin_amdgcn_wave_barrier();  // before next tile's staging writes
    }
}

extern "C" void kernel_launch(void* const* d_in, const int* in_sizes, int n_in,
                              void* d_out, int out_size, void* d_ws, size_t ws_size,
                              hipStream_t stream) {
    const float* t_p   = (const float*)d_in[0];
    const float* z     = (const float*)d_in[1];
    // d_in[2] = logp (unused)
    const float* ctx   = (const float*)d_in[3];
    const float* eps   = (const float*)d_in[4];
    const float* W_in  = (const float*)d_in[5];
    const float* b_in  = (const float*)d_in[6];
    const float* W_h1  = (const float*)d_in[7];
    const float* b_h1  = (const float*)d_in[8];
    const float* W_h2  = (const float*)d_in[9];
    const float* b_h2  = (const float*)d_in[10];
    const float* W_out = (const float*)d_in[11];
    const float* b_out = (const float*)d_in[12];
    const float* os_p  = (const float*)d_in[13];
    _Float16* ws = (_Float16*)d_ws;
    float* out = (float*)d_out;

    static bool attr_set = false;
    if (!attr_set) {
        (void)hipFuncSetAttribute((const void*)fused_kernel,
                                  hipFuncAttributeMaxDynamicSharedMemorySize,
                                  LDS_BYTES);
        attr_set = true;
    }

    prep_kernel<<<(WS_TOTAL + 255) / 256, 256, 0, stream>>>(
        W_in, W_h1, W_h2, W_out, ws);
    fused_kernel<<<GRID, 512, LDS_BYTES, stream>>>(
        t_p, z, ctx, eps, b_in, b_h1, b_h2, b_out, os_p, ws, out);
}

// Round 4
// 501.116 us; speedup vs baseline: 1.7971x; 1.2619x over previous
//
#include <hip/hip_runtime.h>

// ---------------------------------------------------------------------------
// Fused CNF ODE func: f = MLP(z,ctx,t), neg_div = -eps^T d(f.eps)/dz
// B=500000, DIM=3, COND=64, IN=68, HID=128.
//
// Round 4: feat-major register-chained MFMA (R3 design, builtin name fixed).
// batch = N (lane dim, 2 cols of 16 per wave = 32 rows/tile), features=M/K.
// C-tiles of each GEMM, packed f32->f16, ARE the B-fragments of the next
// GEMM (16x16x16 duality: C[4q+i][l15] == B[4q+j][l15]). No LDS activation
// traffic, no barriers in the main loop. Weights = A-fragments from LDS
// (fwd W^T, bwd W original); WB1 streamed from L2. Outputs staged per-wave
// in LDS -> dense dwordx4 global stores.
// ---------------------------------------------------------------------------

#define B_N    500000
#define NT32   15625          // 500000 / 32 exact
#define GRID   256
#define NSTR   (GRID * 8)

// ws f16-element offsets
#define WS_WB1   0            // [128][128] W_h1 original (L2-streamed, bwd2)
#define WS_LDS   16384        // start of block copied to LDS
// offsets WITHIN the LDS block (f16 elements):
#define L_WFIN   0            // [128][72] W_in^T  (k:0..63 ctx,64..66 z,67 t) +4 pad
#define L_WF1    9232         // [128][132] W_h1^T
#define L_WF2    26128        // [128][132] W_h2^T
#define L_WB2    43024        // [128][132] W_h2 original (bwd3 A)
#define L_WOUTP  59920        // [128][20]  W_out padded (u3pre A, k<3 real)
#define L_WOUTT  62480        // [16][132]  W_out^T (f A, rows<3 real)
#define L_WIN3   64592        // [16][132]  W_in rows 0..2 (gz A)
#define L_F16END 66704
#define WS_F16END (WS_LDS + L_F16END)       // 83088 f16 elements
#define N_BIAS   384                        // f32: b_in|b_h1|b_h2, after f16 blk
#define PREP_N   (WS_F16END + N_BIAS)       // 83472 work items

// LDS: f16 block 133408 B + bias 1536 B + outstage 8*512 B = 139040 B
#define LDS_BYTES 139040
#define COPY16    8434        // (133408+1536)/16 uint4 staged ws->LDS

typedef _Float16 f16x4 __attribute__((ext_vector_type(4)));
typedef float    f32x4 __attribute__((ext_vector_type(4)));

union U4 { f16x4 v; _Float16 e[4]; uint2 d; };

static __device__ inline f16x4 lds_a4(const _Float16* p) {
    U4 u; u.d = *reinterpret_cast<const uint2*>(p); return u.v;
}
static __device__ inline f16x4 g_a4(const _Float16* p) {
    U4 u; u.d = *reinterpret_cast<const uint2*>(p); return u.v;
}

#define MFMA(a, b, c) __builtin_amdgcn_mfma_f32_16x16x16f16((a), (b), (c), 0, 0, 0)

static __device__ inline float ftanh(float x) {
    float e = __expf(2.f * x);
    return 1.f - 2.f * __builtin_amdgcn_rcpf(e + 1.f);
}

// ---------------------------------------------------------------------------
// Prep: fp32 weights -> f16 ws arrays + f32 biases
// ---------------------------------------------------------------------------
__global__ void prep_kernel(const float* __restrict__ W_in,
                            const float* __restrict__ W_h1,
                            const float* __restrict__ W_h2,
                            const float* __restrict__ W_out,
                            const float* __restrict__ b_in,
                            const float* __restrict__ b_h1,
                            const float* __restrict__ b_h2,
                            _Float16* __restrict__ ws) {
    int i = blockIdx.x * 256 + threadIdx.x;
    if (i >= PREP_N) return;
    if (i >= WS_F16END) {                       // bias f32 region
        int bi = i - WS_F16END;
        float* bp = reinterpret_cast<float*>(ws + WS_F16END);
        bp[bi] = (bi < 128) ? b_in[bi] : (bi < 256) ? b_h1[bi - 128]
                                                    : b_h2[bi - 256];
        return;
    }
    float v = 0.f;
    if (i < WS_LDS) {                           // WB1 = W_h1 flat [128][128]
        v = W_h1[i];
    } else {
        int j = i - WS_LDS;
        if (j < L_WF1) {                        // WFIN [128][72]
            int n = j / 72, k = j - n * 72;
            if (n < 128) {
                if      (k < 64)  v = W_in[(3 + k) * 128 + n];
                else if (k < 67)  v = W_in[(k - 64) * 128 + n];
                else if (k == 67) v = W_in[67 * 128 + n];
            }
        } else if (j < L_WF2) {                 // WF1 = W_h1^T [128][132]
            int j2 = j - L_WF1; int n = j2 / 132, a = j2 - n * 132;
            if (a < 128) v = W_h1[a * 128 + n];
        } else if (j < L_WB2) {                 // WF2 = W_h2^T [128][132]
            int j2 = j - L_WF2; int n = j2 / 132, a = j2 - n * 132;
            if (a < 128) v = W_h2[a * 128 + n];
        } else if (j < L_WOUTP) {               // WB2 = W_h2 [128][132]
            int j2 = j - L_WB2; int r = j2 / 132, b = j2 - r * 132;
            if (b < 128) v = W_h2[r * 128 + b];
        } else if (j < L_WOUTT) {               // WOUTP [128][20]
            int j2 = j - L_WOUTP; int n = j2 / 20, k = j2 - n * 20;
            if (k < 3) v = W_out[n * 3 + k];
        } else if (j < L_WIN3) {                // WOUTT [16][132]
            int j2 = j - L_WOUTT; int d = j2 / 132, n = j2 - d * 132;
            if (d < 3 && n < 128) v = W_out[n * 3 + d];
        } else {                                // WIN3 [16][132]
            int j2 = j - L_WIN3; int d = j2 / 132, a = j2 - d * 132;
            if (d < 3 && a < 128) v = W_in[d * 128 + a];
        }
    }
    ws[i] = (_Float16)v;
}

// ---------------------------------------------------------------------------
// Main fused kernel — feat-major register chain, no main-loop barriers
// ---------------------------------------------------------------------------
__global__ __launch_bounds__(512, 2) void fused_kernel(
        const float* __restrict__ t_p,  const float* __restrict__ z,
        const float* __restrict__ ctx,  const float* __restrict__ eps,
        const float* __restrict__ b_out, const float* __restrict__ os_p,
        const _Float16* __restrict__ ws, float* __restrict__ out) {
    extern __shared__ _Float16 smem[];
    const int tid  = threadIdx.x;
    const int wave = tid >> 6;
    const int lane = tid & 63;
    const int l15  = lane & 15;
    const int q    = lane >> 4;

    // stage weights + biases ws -> LDS (one contiguous copy)
    {
        const uint4* src = reinterpret_cast<const uint4*>(ws + WS_LDS);
        uint4* dst = reinterpret_cast<uint4*>(smem);
        for (int i = tid; i < COPY16; i += 512) dst[i] = src[i];
    }
    __syncthreads();   // the only block barrier

    const _Float16* WFIN  = smem + L_WFIN;
    const _Float16* WF1   = smem + L_WF1;
    const _Float16* WF2   = smem + L_WF2;
    const _Float16* WB2   = smem + L_WB2;
    const _Float16* WOUTP = smem + L_WOUTP;
    const _Float16* WOUTT = smem + L_WOUTT;
    const _Float16* WIN3  = smem + L_WIN3;
    const float* biasf = reinterpret_cast<const float*>(smem + L_F16END);
    float* outst = const_cast<float*>(biasf) + N_BIAS + wave * 128;

    const _Float16* WB1g = ws + WS_WB1;

    const float tval = t_p[0];
    const float os   = os_p[0];
    const float bo0 = b_out[0], bo1 = b_out[1], bo2 = b_out[2];
    float* out_f  = out;
    float* out_nd = out + (size_t)B_N * 3;

    const f32x4 zero4 = {0.f, 0.f, 0.f, 0.f};

    for (int t = blockIdx.x * 8 + wave; t < NT32; t += NSTR) {
        const int gb = t * 32;

        // ---- eps fragments (q==0 lanes hold batch row gb+16c+l15)
        U4 epsb[2];
        float ee[2][3];
        #pragma unroll
        for (int c = 0; c < 2; ++c) {
            epsb[c].d.x = 0u; epsb[c].d.y = 0u;
            ee[c][0] = ee[c][1] = ee[c][2] = 0.f;
            if (q == 0) {
                const float* ep = eps + (size_t)(gb + 16 * c + l15) * 3;
                ee[c][0] = ep[0]; ee[c][1] = ep[1]; ee[c][2] = ep[2];
                epsb[c].e[0] = (_Float16)ee[c][0];
                epsb[c].e[1] = (_Float16)ee[c][1];
                epsb[c].e[2] = (_Float16)ee[c][2];
            }
        }

        // ================= L1: X1 = W_in^T @ inp^T  (K=80) =================
        f32x4 acc[8][2];
        #pragma unroll
        for (int m = 0; m < 8; ++m) { acc[m][0] = zero4; acc[m][1] = zero4; }

        #pragma unroll
        for (int kk = 0; kk < 4; ++kk) {         // ctx chunks k=16kk..16kk+15
            U4 b[2];
            #pragma unroll
            for (int c = 0; c < 2; ++c) {
                const float4 cv = *reinterpret_cast<const float4*>(
                    ctx + (size_t)(gb + 16 * c + l15) * 64 + kk * 16 + 4 * q);
                b[c].e[0] = (_Float16)cv.x; b[c].e[1] = (_Float16)cv.y;
                b[c].e[2] = (_Float16)cv.z; b[c].e[3] = (_Float16)cv.w;
            }
            #pragma unroll
            for (int m = 0; m < 8; ++m) {
                f16x4 a = lds_a4(WFIN + (16 * m + l15) * 72 + kk * 16 + 4 * q);
                acc[m][0] = MFMA(a, b[0].v, acc[m][0]);
                acc[m][1] = MFMA(a, b[1].v, acc[m][1]);
            }
        }
        {                                        // chunk 4: z + t (q==0 only)
            U4 b[2];
            #pragma unroll
            for (int c = 0; c < 2; ++c) {
                b[c].d.x = 0u; b[c].d.y = 0u;
                if (q == 0) {
                    const float* zp = z + (size_t)(gb + 16 * c + l15) * 3;
                    b[c].e[0] = (_Float16)zp[0]; b[c].e[1] = (_Float16)zp[1];
                    b[c].e[2] = (_Float16)zp[2]; b[c].e[3] = (_Float16)tval;
                }
            }
            #pragma unroll
            for (int m = 0; m < 8; ++m) {
                f16x4 a = lds_a4(WFIN + (16 * m + l15) * 72 + 64 + 4 * q);
                acc[m][0] = MFMA(a, b[0].v, acc[m][0]);
                acc[m][1] = MFMA(a, b[1].v, acc[m][1]);
            }
        }
        U4 h1p[8][2];
        #pragma unroll
        for (int m = 0; m < 8; ++m) {
            const float4 bb = *reinterpret_cast<const float4*>(
                biasf + 0 + 16 * m + 4 * q);
            #pragma unroll
            for (int c = 0; c < 2; ++c) {
                h1p[m][c].e[0] = (_Float16)ftanh(acc[m][c][0] + bb.x);
                h1p[m][c].e[1] = (_Float16)ftanh(acc[m][c][1] + bb.y);
                h1p[m][c].e[2] = (_Float16)ftanh(acc[m][c][2] + bb.z);
                h1p[m][c].e[3] = (_Float16)ftanh(acc[m][c][3] + bb.w);
            }
        }

        // ================= L2: H2 = tanh(W_h1^T @ H1 + b1) =================
        #pragma unroll
        for (int m = 0; m < 8; ++m) { acc[m][0] = zero4; acc[m][1] = zero4; }
        #pragma unroll
        for (int kk = 0; kk < 8; ++kk) {
            #pragma unroll
            for (int m = 0; m < 8; ++m) {
                f16x4 a = lds_a4(WF1 + (16 * m + l15) * 132 + 16 * kk + 4 * q);
                acc[m][0] = MFMA(a, h1p[kk][0].v, acc[m][0]);
                acc[m][1] = MFMA(a, h1p[kk][1].v, acc[m][1]);
            }
        }
        U4 h2p[8][2];
        #pragma unroll
        for (int m = 0; m < 8; ++m) {
            const float4 bb = *reinterpret_cast<const float4*>(
                biasf + 128 + 16 * m + 4 * q);
            #pragma unroll
            for (int c = 0; c < 2; ++c) {
                h2p[m][c].e[0] = (_Float16)ftanh(acc[m][c][0] + bb.x);
                h2p[m][c].e[1] = (_Float16)ftanh(acc[m][c][1] + bb.y);
                h2p[m][c].e[2] = (_Float16)ftanh(acc[m][c][2] + bb.z);
                h2p[m][c].e[3] = (_Float16)ftanh(acc[m][c][3] + bb.w);
            }
        }

        // ================= L3: H3 = tanh(W_h2^T @ H2 + b2) =================
        #pragma unroll
        for (int m = 0; m < 8; ++m) { acc[m][0] = zero4; acc[m][1] = zero4; }
        #pragma unroll
        for (int kk = 0; kk < 8; ++kk) {
            #pragma unroll
            for (int m = 0; m < 8; ++m) {
                f16x4 a = lds_a4(WF2 + (16 * m + l15) * 132 + 16 * kk + 4 * q);
                acc[m][0] = MFMA(a, h2p[kk][0].v, acc[m][0]);
                acc[m][1] = MFMA(a, h2p[kk][1].v, acc[m][1]);
            }
        }
        // u3pre = W_out @ eps^T (K=16, k<3 real), then h3 / u3 epilogue
        U4 h3p[8][2], u3p[8][2];
        #pragma unroll
        for (int m = 0; m < 8; ++m) {
            const float4 bb = *reinterpret_cast<const float4*>(
                biasf + 256 + 16 * m + 4 * q);
            f16x4 a3 = lds_a4(WOUTP + (16 * m + l15) * 20 + 4 * q);
            #pragma unroll
            for (int c = 0; c < 2; ++c) {
                f32x4 up = MFMA(a3, epsb[c].v, zero4);
                #pragma unroll
                for (int i = 0; i < 4; ++i) {
                    float bi = (i == 0) ? bb.x : (i == 1) ? bb.y
                              : (i == 2) ? bb.z : bb.w;
                    float h = ftanh(acc[m][c][i] + bi);
                    h3p[m][c].e[i] = (_Float16)h;
                    u3p[m][c].e[i] = (_Float16)(os * up[i] * (1.f - h * h));
                }
            }
        }

        // ================= f = (H3^T @ W_out + b_out) * os =================
        {
            f32x4 f0 = zero4, f1 = zero4;
            #pragma unroll
            for (int kk = 0; kk < 8; ++kk) {
                f16x4 a = lds_a4(WOUTT + l15 * 132 + 16 * kk + 4 * q);
                f0 = MFMA(a, h3p[kk][0].v, f0);
                f1 = MFMA(a, h3p[kk][1].v, f1);
            }
            if (q == 0) {
                outst[(0 * 16 + l15) * 3 + 0] = (f0[0] + bo0) * os;
                outst[(0 * 16 + l15) * 3 + 1] = (f0[1] + bo1) * os;
                outst[(0 * 16 + l15) * 3 + 2] = (f0[2] + bo2) * os;
                outst[(1 * 16 + l15) * 3 + 0] = (f1[0] + bo0) * os;
                outst[(1 * 16 + l15) * 3 + 1] = (f1[1] + bo1) * os;
                outst[(1 * 16 + l15) * 3 + 2] = (f1[2] + bo2) * os;
            }
        }

        // ================= bwd3: U2 = (W_h2 @ U3) * (1-h2^2) ===============
        #pragma unroll
        for (int m = 0; m < 8; ++m) { acc[m][0] = zero4; acc[m][1] = zero4; }
        #pragma unroll
        for (int kk = 0; kk < 8; ++kk) {
            #pragma unroll
            for (int m = 0; m < 8; ++m) {
                f16x4 a = lds_a4(WB2 + (16 * m + l15) * 132 + 16 * kk + 4 * q);
                acc[m][0] = MFMA(a, u3p[kk][0].v, acc[m][0]);
                acc[m][1] = MFMA(a, u3p[kk][1].v, acc[m][1]);
            }
        }
        #pragma unroll
        for (int m = 0; m < 8; ++m)
            #pragma unroll
            for (int c = 0; c < 2; ++c) {
                U4 u2;
                #pragma unroll
                for (int i = 0; i < 4; ++i) {
                    float h = (float)h2p[m][c].e[i];
                    u2.e[i] = (_Float16)(acc[m][c][i] * (1.f - h * h));
                }
                h2p[m][c] = u2;    // reuse registers: h2p becomes u2p
            }

        // ============ bwd2: U1 = (W_h1 @ U2) * (1-h1^2)  [A from L2] =======
        #pragma unroll
        for (int m = 0; m < 8; ++m) { acc[m][0] = zero4; acc[m][1] = zero4; }
        #pragma unroll
        for (int kk = 0; kk < 8; ++kk) {
            #pragma unroll
            for (int m = 0; m < 8; ++m) {
                f16x4 a = g_a4(WB1g + (16 * m + l15) * 128 + 16 * kk + 4 * q);
                acc[m][0] = MFMA(a, h2p[kk][0].v, acc[m][0]);
                acc[m][1] = MFMA(a, h2p[kk][1].v, acc[m][1]);
            }
        }
        #pragma unroll
        for (int m = 0; m < 8; ++m)
            #pragma unroll
            for (int c = 0; c < 2; ++c) {
                U4 u1;
                #pragma unroll
                for (int i = 0; i < 4; ++i) {
                    float h = (float)h1p[m][c].e[i];
                    u1.e[i] = (_Float16)(acc[m][c][i] * (1.f - h * h));
                }
                h1p[m][c] = u1;    // reuse registers: h1p becomes u1p
            }

        // ======= gz = W_in[0:3] @ U1 ; neg_div = -sum(gz * eps) ============
        {
            f32x4 g0 = zero4, g1 = zero4;
            #pragma unroll
            for (int kk = 0; kk < 8; ++kk) {
                f16x4 a = lds_a4(WIN3 + l15 * 132 + 16 * kk + 4 * q);
                g0 = MFMA(a, h1p[kk][0].v, g0);
                g1 = MFMA(a, h1p[kk][1].v, g1);
            }
            if (q == 0) {
                outst[96 + l15]      =
                    -(g0[0] * ee[0][0] + g0[1] * ee[0][1] + g0[2] * ee[0][2]);
                outst[96 + 16 + l15] =
                    -(g1[0] * ee[1][0] + g1[1] * ee[1][1] + g1[2] * ee[1][2]);
            }
        }

        // ---- dense global stores from LDS staging (in-order same-wave DS)
        if (lane < 24) {
            float4 v = *reinterpret_cast<const float4*>(outst + lane * 4);
            *reinterpret_cast<float4*>(out_f + (size_t)gb * 3 + lane * 4) = v;
        } else if (lane < 32) {
            int l = lane - 24;
            float4 v = *reinterpret_cast<const float4*>(outst + 96 + l * 4);
            *reinterpret_cast<float4*>(out_nd + gb + l * 4) = v;
        }
    }
}

extern "C" void kernel_launch(void* const* d_in, const int* in_sizes, int n_in,
                              void* d_out, int out_size, void* d_ws, size_t ws_size,
                              hipStream_t stream) {
    const float* t_p   = (const float*)d_in[0];
    const float* z     = (const float*)d_in[1];
    // d_in[2] = logp (unused)
    const float* ctx   = (const float*)d_in[3];
    const float* eps   = (const float*)d_in[4];
    const float* W_in  = (const float*)d_in[5];
    const float* b_in  = (const float*)d_in[6];
    const float* W_h1  = (const float*)d_in[7];
    const float* b_h1  = (const float*)d_in[8];
    const float* W_h2  = (const float*)d_in[9];
    const float* b_h2  = (const float*)d_in[10];
    const float* W_out = (const float*)d_in[11];
    const float* b_out = (const float*)d_in[12];
    const float* os_p  = (const float*)d_in[13];
    _Float16* ws = (_Float16*)d_ws;
    float* out = (float*)d_out;

    static bool attr_set = false;
    if (!attr_set) {
        (void)hipFuncSetAttribute((const void*)fused_kernel,
                                  hipFuncAttributeMaxDynamicSharedMemorySize,
                                  LDS_BYTES);
        attr_set = true;
    }

    prep_kernel<<<(PREP_N + 255) / 256, 256, 0, stream>>>(
        W_in, W_h1, W_h2, W_out, b_in, b_h1, b_h2, ws);
    fused_kernel<<<GRID, 512, LDS_BYTES, stream>>>(
        t_p, z, ctx, eps, b_out, os_p, ws, out);
}

// Round 5
// 335.444 us; speedup vs baseline: 2.6846x; 1.4939x over previous
//
#include <hip/hip_runtime.h>

// ---------------------------------------------------------------------------
// Fused CNF ODE func: f = MLP(z,ctx,t), neg_div = -eps^T d(f.eps)/dz
// B=500000, DIM=3, COND=64, IN=68, HID=128.
//
// Round 5: R4 feat-major register chain, de-spilled.
//  - __launch_bounds__(512,1): VGPR budget 256 (live ~190) -> no scratch
//    spills (R4: 128-cap caused +71MB writes / +196MB reads of spill traffic).
//  - ALL weights LDS-resident (W_h1 bwd copy moved in; trimmed WFIN/WOUTP/
//    WOUTT/WIN3 exploiting zero-B / discarded-D garbage tolerance). 159792 B.
//  - neg_div written directly (coalesced); f staged via LDS -> dwordx4.
// ---------------------------------------------------------------------------

#define B_N    500000
#define NT32   15625          // 500000 / 32 exact
#define GRID   256
#define NSTR   (GRID * 8)

// LDS/ws f16-element offsets (identical layout in ws and LDS)
#define L_WFIN   0            // [128][68]  W_in^T (k:0..63 ctx,64..66 z,67 t)
#define L_WF1    8704         // [128][132] W_h1^T (fwd L2 A)
#define L_WF2    25600        // [128][132] W_h2^T (fwd L3 A)
#define L_WB2    42496        // [128][132] W_h2 original (bwd3 A)
#define L_WB1    59392        // [128][132] W_h1 original (bwd2 A)
#define L_WOUTP  76288        // [128][4]   W_out rows (u3pre A, k<3 real)
#define L_WOUTT  76800        // [3][132]   W_out^T (f A, rows 0..2)
#define L_WIN3   77196        // [3][132]   W_in rows 0..2 (gz A)
#define L_F16END 77592
#define N_BIAS   384                         // f32 b_in|b_h1|b_h2
#define PREP_N   (L_F16END + N_BIAS)         // 77976 work items
#define BIAS_BYTE   155184                   // L_F16END*2
#define OUTST_BYTE  156720                   // BIAS_BYTE + 1536
#define LDS_BYTES   159792                   // OUTST_BYTE + 8*96*4
#define COPY16      9795                     // 156720/16 uint4 ws->LDS

typedef _Float16 f16x4 __attribute__((ext_vector_type(4)));
typedef float    f32x4 __attribute__((ext_vector_type(4)));

union U4 { f16x4 v; _Float16 e[4]; uint2 d; };

static __device__ inline f16x4 lds_a4(const _Float16* p) {
    U4 u; u.d = *reinterpret_cast<const uint2*>(p); return u.v;
}

#define MFMA(a, b, c) __builtin_amdgcn_mfma_f32_16x16x16f16((a), (b), (c), 0, 0, 0)

static __device__ inline float ftanh(float x) {
    float e = __expf(2.f * x);
    return 1.f - 2.f * __builtin_amdgcn_rcpf(e + 1.f);
}

// ---------------------------------------------------------------------------
// Prep: fp32 weights -> f16 ws arrays + f32 biases
// ---------------------------------------------------------------------------
__global__ void prep_kernel(const float* __restrict__ W_in,
                            const float* __restrict__ W_h1,
                            const float* __restrict__ W_h2,
                            const float* __restrict__ W_out,
                            const float* __restrict__ b_in,
                            const float* __restrict__ b_h1,
                            const float* __restrict__ b_h2,
                            _Float16* __restrict__ ws) {
    int i = blockIdx.x * 256 + threadIdx.x;
    if (i >= PREP_N) return;
    if (i >= L_F16END) {                        // bias f32 region
        int bi = i - L_F16END;
        float* bp = reinterpret_cast<float*>(ws + L_F16END);
        bp[bi] = (bi < 128) ? b_in[bi] : (bi < 256) ? b_h1[bi - 128]
                                                    : b_h2[bi - 256];
        return;
    }
    float v = 0.f;
    if (i < L_WF1) {                            // WFIN [128][68]
        int n = i / 68, k = i - n * 68;
        if      (k < 64)  v = W_in[(3 + k) * 128 + n];
        else if (k < 67)  v = W_in[(k - 64) * 128 + n];
        else              v = W_in[67 * 128 + n];
    } else if (i < L_WF2) {                     // WF1 = W_h1^T [128][132]
        int j = i - L_WF1; int n = j / 132, a = j - n * 132;
        if (a < 128) v = W_h1[a * 128 + n];
    } else if (i < L_WB2) {                     // WF2 = W_h2^T [128][132]
        int j = i - L_WF2; int n = j / 132, a = j - n * 132;
        if (a < 128) v = W_h2[a * 128 + n];
    } else if (i < L_WB1) {                     // WB2 = W_h2 [128][132]
        int j = i - L_WB2; int r = j / 132, b = j - r * 132;
        if (b < 128) v = W_h2[r * 128 + b];
    } else if (i < L_WOUTP) {                   // WB1 = W_h1 [128][132]
        int j = i - L_WB1; int r = j / 132, b = j - r * 132;
        if (b < 128) v = W_h1[r * 128 + b];
    } else if (i < L_WOUTT) {                   // WOUTP [128][4]
        int j = i - L_WOUTP; int n = j >> 2, k = j & 3;
        if (k < 3) v = W_out[n * 3 + k];
    } else if (i < L_WIN3) {                    // WOUTT [3][132]
        int j = i - L_WOUTT; int d = j / 132, n = j - d * 132;
        if (n < 128) v = W_out[n * 3 + d];
    } else {                                    // WIN3 [3][132]
        int j = i - L_WIN3; int d = j / 132, a = j - d * 132;
        if (a < 128) v = W_in[d * 128 + a];
    }
    ws[i] = (_Float16)v;
}

// ---------------------------------------------------------------------------
// Main fused kernel — feat-major register chain, no main-loop barriers
// ---------------------------------------------------------------------------
__global__ __launch_bounds__(512, 1) void fused_kernel(
        const float* __restrict__ t_p,  const float* __restrict__ z,
        const float* __restrict__ ctx,  const float* __restrict__ eps,
        const float* __restrict__ b_out, const float* __restrict__ os_p,
        const _Float16* __restrict__ ws, float* __restrict__ out) {
    extern __shared__ _Float16 smem[];
    const int tid  = threadIdx.x;
    const int wave = tid >> 6;
    const int lane = tid & 63;
    const int l15  = lane & 15;
    const int q    = lane >> 4;

    // stage weights + biases ws -> LDS (one contiguous copy)
    {
        const uint4* src = reinterpret_cast<const uint4*>(ws);
        uint4* dst = reinterpret_cast<uint4*>(smem);
        for (int i = tid; i < COPY16; i += 512) dst[i] = src[i];
    }
    __syncthreads();   // the only block barrier

    const _Float16* WFIN  = smem + L_WFIN;
    const _Float16* WF1   = smem + L_WF1;
    const _Float16* WF2   = smem + L_WF2;
    const _Float16* WB2   = smem + L_WB2;
    const _Float16* WB1   = smem + L_WB1;
    const _Float16* WOUTP = smem + L_WOUTP;
    const _Float16* WOUTT = smem + L_WOUTT;
    const _Float16* WIN3  = smem + L_WIN3;
    const float* biasf =
        reinterpret_cast<const float*>(reinterpret_cast<char*>(smem) + BIAS_BYTE);
    float* outst =
        reinterpret_cast<float*>(reinterpret_cast<char*>(smem) + OUTST_BYTE)
        + wave * 96;

    const float tval = t_p[0];
    const float os   = os_p[0];
    const float bo0 = b_out[0], bo1 = b_out[1], bo2 = b_out[2];
    float* out_f  = out;
    float* out_nd = out + (size_t)B_N * 3;

    const f32x4 zero4 = {0.f, 0.f, 0.f, 0.f};

    for (int t = blockIdx.x * 8 + wave; t < NT32; t += NSTR) {
        const int gb = t * 32;

        // ---- eps fragments (q==0 lanes hold batch row gb+16c+l15)
        U4 epsb[2];
        float ee[2][3];
        #pragma unroll
        for (int c = 0; c < 2; ++c) {
            epsb[c].d.x = 0u; epsb[c].d.y = 0u;
            ee[c][0] = ee[c][1] = ee[c][2] = 0.f;
            if (q == 0) {
                const float* ep = eps + (size_t)(gb + 16 * c + l15) * 3;
                ee[c][0] = ep[0]; ee[c][1] = ep[1]; ee[c][2] = ep[2];
                epsb[c].e[0] = (_Float16)ee[c][0];
                epsb[c].e[1] = (_Float16)ee[c][1];
                epsb[c].e[2] = (_Float16)ee[c][2];
            }
        }

        // ================= L1: X1 = W_in^T @ inp^T  (K=80) =================
        f32x4 acc[8][2];
        #pragma unroll
        for (int m = 0; m < 8; ++m) { acc[m][0] = zero4; acc[m][1] = zero4; }

        #pragma unroll
        for (int kk = 0; kk < 4; ++kk) {         // ctx chunks k=16kk..16kk+15
            U4 b[2];
            #pragma unroll
            for (int c = 0; c < 2; ++c) {
                const float4 cv = *reinterpret_cast<const float4*>(
                    ctx + (size_t)(gb + 16 * c + l15) * 64 + kk * 16 + 4 * q);
                b[c].e[0] = (_Float16)cv.x; b[c].e[1] = (_Float16)cv.y;
                b[c].e[2] = (_Float16)cv.z; b[c].e[3] = (_Float16)cv.w;
            }
            #pragma unroll
            for (int m = 0; m < 8; ++m) {
                f16x4 a = lds_a4(WFIN + (16 * m + l15) * 68 + kk * 16 + 4 * q);
                acc[m][0] = MFMA(a, b[0].v, acc[m][0]);
                acc[m][1] = MFMA(a, b[1].v, acc[m][1]);
            }
        }
        {                                        // chunk 4: z + t (q==0 only)
            U4 b[2];
            #pragma unroll
            for (int c = 0; c < 2; ++c) {
                b[c].d.x = 0u; b[c].d.y = 0u;
                if (q == 0) {
                    const float* zp = z + (size_t)(gb + 16 * c + l15) * 3;
                    b[c].e[0] = (_Float16)zp[0]; b[c].e[1] = (_Float16)zp[1];
                    b[c].e[2] = (_Float16)zp[2]; b[c].e[3] = (_Float16)tval;
                }
            }
            // q>=1 lanes read past row width 68 -> neighbor-row garbage * 0
            #pragma unroll
            for (int m = 0; m < 8; ++m) {
                f16x4 a = lds_a4(WFIN + (16 * m + l15) * 68 + 64 + 4 * q);
                acc[m][0] = MFMA(a, b[0].v, acc[m][0]);
                acc[m][1] = MFMA(a, b[1].v, acc[m][1]);
            }
        }
        U4 h1p[8][2];
        #pragma unroll
        for (int m = 0; m < 8; ++m) {
            const float4 bb = *reinterpret_cast<const float4*>(
                biasf + 0 + 16 * m + 4 * q);
            #pragma unroll
            for (int c = 0; c < 2; ++c) {
                h1p[m][c].e[0] = (_Float16)ftanh(acc[m][c][0] + bb.x);
                h1p[m][c].e[1] = (_Float16)ftanh(acc[m][c][1] + bb.y);
                h1p[m][c].e[2] = (_Float16)ftanh(acc[m][c][2] + bb.z);
                h1p[m][c].e[3] = (_Float16)ftanh(acc[m][c][3] + bb.w);
            }
        }

        // ================= L2: H2 = tanh(W_h1^T @ H1 + b1) =================
        #pragma unroll
        for (int m = 0; m < 8; ++m) { acc[m][0] = zero4; acc[m][1] = zero4; }
        #pragma unroll
        for (int kk = 0; kk < 8; ++kk) {
            #pragma unroll
            for (int m = 0; m < 8; ++m) {
                f16x4 a = lds_a4(WF1 + (16 * m + l15) * 132 + 16 * kk + 4 * q);
                acc[m][0] = MFMA(a, h1p[kk][0].v, acc[m][0]);
                acc[m][1] = MFMA(a, h1p[kk][1].v, acc[m][1]);
            }
        }
        U4 h2p[8][2];
        #pragma unroll
        for (int m = 0; m < 8; ++m) {
            const float4 bb = *reinterpret_cast<const float4*>(
                biasf + 128 + 16 * m + 4 * q);
            #pragma unroll
            for (int c = 0; c < 2; ++c) {
                h2p[m][c].e[0] = (_Float16)ftanh(acc[m][c][0] + bb.x);
                h2p[m][c].e[1] = (_Float16)ftanh(acc[m][c][1] + bb.y);
                h2p[m][c].e[2] = (_Float16)ftanh(acc[m][c][2] + bb.z);
                h2p[m][c].e[3] = (_Float16)ftanh(acc[m][c][3] + bb.w);
            }
        }

        // ================= L3: H3 = tanh(W_h2^T @ H2 + b2) =================
        #pragma unroll
        for (int m = 0; m < 8; ++m) { acc[m][0] = zero4; acc[m][1] = zero4; }
        #pragma unroll
        for (int kk = 0; kk < 8; ++kk) {
            #pragma unroll
            for (int m = 0; m < 8; ++m) {
                f16x4 a = lds_a4(WF2 + (16 * m + l15) * 132 + 16 * kk + 4 * q);
                acc[m][0] = MFMA(a, h2p[kk][0].v, acc[m][0]);
                acc[m][1] = MFMA(a, h2p[kk][1].v, acc[m][1]);
            }
        }
        // u3pre = W_out @ eps^T (K=16, k<3 real), then h3 / u3 epilogue
        U4 h3p[8][2], u3p[8][2];
        #pragma unroll
        for (int m = 0; m < 8; ++m) {
            const float4 bb = *reinterpret_cast<const float4*>(
                biasf + 256 + 16 * m + 4 * q);
            f16x4 a3 = lds_a4(WOUTP + (16 * m + l15) * 4 + 4 * q);
            #pragma unroll
            for (int c = 0; c < 2; ++c) {
                f32x4 up = MFMA(a3, epsb[c].v, zero4);
                #pragma unroll
                for (int i = 0; i < 4; ++i) {
                    float bi = (i == 0) ? bb.x : (i == 1) ? bb.y
                              : (i == 2) ? bb.z : bb.w;
                    float h = ftanh(acc[m][c][i] + bi);
                    h3p[m][c].e[i] = (_Float16)h;
                    u3p[m][c].e[i] = (_Float16)(os * up[i] * (1.f - h * h));
                }
            }
        }

        // ================= f = (H3^T @ W_out + b_out) * os =================
        {
            f32x4 f0 = zero4, f1 = zero4;
            #pragma unroll
            for (int kk = 0; kk < 8; ++kk) {
                f16x4 a = lds_a4(WOUTT + l15 * 132 + 16 * kk + 4 * q);
                f0 = MFMA(a, h3p[kk][0].v, f0);
                f1 = MFMA(a, h3p[kk][1].v, f1);
            }
            if (q == 0) {
                outst[(0 * 16 + l15) * 3 + 0] = (f0[0] + bo0) * os;
                outst[(0 * 16 + l15) * 3 + 1] = (f0[1] + bo1) * os;
                outst[(0 * 16 + l15) * 3 + 2] = (f0[2] + bo2) * os;
                outst[(1 * 16 + l15) * 3 + 0] = (f1[0] + bo0) * os;
                outst[(1 * 16 + l15) * 3 + 1] = (f1[1] + bo1) * os;
                outst[(1 * 16 + l15) * 3 + 2] = (f1[2] + bo2) * os;
            }
        }

        // ================= bwd3: U2 = (W_h2 @ U3) * (1-h2^2) ===============
        #pragma unroll
        for (int m = 0; m < 8; ++m) { acc[m][0] = zero4; acc[m][1] = zero4; }
        #pragma unroll
        for (int kk = 0; kk < 8; ++kk) {
            #pragma unroll
            for (int m = 0; m < 8; ++m) {
                f16x4 a = lds_a4(WB2 + (16 * m + l15) * 132 + 16 * kk + 4 * q);
                acc[m][0] = MFMA(a, u3p[kk][0].v, acc[m][0]);
                acc[m][1] = MFMA(a, u3p[kk][1].v, acc[m][1]);
            }
        }
        #pragma unroll
        for (int m = 0; m < 8; ++m)
            #pragma unroll
            for (int c = 0; c < 2; ++c) {
                U4 u2;
                #pragma unroll
                for (int i = 0; i < 4; ++i) {
                    float h = (float)h2p[m][c].e[i];
                    u2.e[i] = (_Float16)(acc[m][c][i] * (1.f - h * h));
                }
                h2p[m][c] = u2;    // h2p becomes u2p
            }

        // ============ bwd2: U1 = (W_h1 @ U2) * (1-h1^2)  [LDS now] =========
        #pragma unroll
        for (int m = 0; m < 8; ++m) { acc[m][0] = zero4; acc[m][1] = zero4; }
        #pragma unroll
        for (int kk = 0; kk < 8; ++kk) {
            #pragma unroll
            for (int m = 0; m < 8; ++m) {
                f16x4 a = lds_a4(WB1 + (16 * m + l15) * 132 + 16 * kk + 4 * q);
                acc[m][0] = MFMA(a, h2p[kk][0].v, acc[m][0]);
                acc[m][1] = MFMA(a, h2p[kk][1].v, acc[m][1]);
            }
        }
        #pragma unroll
        for (int m = 0; m < 8; ++m)
            #pragma unroll
            for (int c = 0; c < 2; ++c) {
                U4 u1;
                #pragma unroll
                for (int i = 0; i < 4; ++i) {
                    float h = (float)h1p[m][c].e[i];
                    u1.e[i] = (_Float16)(acc[m][c][i] * (1.f - h * h));
                }
                h1p[m][c] = u1;    // h1p becomes u1p
            }

        // ======= gz = W_in[0:3] @ U1 ; neg_div = -sum(gz * eps) ============
        {
            f32x4 g0 = zero4, g1 = zero4;
            #pragma unroll
            for (int kk = 0; kk < 8; ++kk) {
                f16x4 a = lds_a4(WIN3 + l15 * 132 + 16 * kk + 4 * q);
                g0 = MFMA(a, h1p[kk][0].v, g0);
                g1 = MFMA(a, h1p[kk][1].v, g1);
            }
            if (q == 0) {   // 16-lane coalesced dword stores, direct
                out_nd[gb + l15] =
                    -(g0[0] * ee[0][0] + g0[1] * ee[0][1] + g0[2] * ee[0][2]);
                out_nd[gb + 16 + l15] =
                    -(g1[0] * ee[1][0] + g1[1] * ee[1][1] + g1[2] * ee[1][2]);
            }
        }

        // ---- dense f stores from LDS staging (in-order same-wave DS)
        if (lane < 24) {
            float4 v = *reinterpret_cast<const float4*>(outst + lane * 4);
            *reinterpret_cast<float4*>(out_f + (size_t)gb * 3 + lane * 4) = v;
        }
    }
}

extern "C" void kernel_launch(void* const* d_in, const int* in_sizes, int n_in,
                              void* d_out, int out_size, void* d_ws, size_t ws_size,
                              hipStream_t stream) {
    const float* t_p   = (const float*)d_in[0];
    const float* z     = (const float*)d_in[1];
    // d_in[2] = logp (unused)
    const float* ctx   = (const float*)d_in[3];
    const float* eps   = (const float*)d_in[4];
    const float* W_in  = (const float*)d_in[5];
    const float* b_in  = (const float*)d_in[6];
    const float* W_h1  = (const float*)d_in[7];
    const float* b_h1  = (const float*)d_in[8];
    const float* W_h2  = (const float*)d_in[9];
    const float* b_h2  = (const float*)d_in[10];
    const float* W_out = (const float*)d_in[11];
    const float* b_out = (const float*)d_in[12];
    const float* os_p  = (const float*)d_in[13];
    _Float16* ws = (_Float16*)d_ws;
    float* out = (float*)d_out;

    static bool attr_set = false;
    if (!attr_set) {
        (void)hipFuncSetAttribute((const void*)fused_kernel,
                                  hipFuncAttributeMaxDynamicSharedMemorySize,
                                  LDS_BYTES);
        attr_set = true;
    }

    prep_kernel<<<(PREP_N + 255) / 256, 256, 0, stream>>>(
        W_in, W_h1, W_h2, W_out, b_in, b_h1, b_h2, ws);
    fused_kernel<<<GRID, 512, LDS_BYTES, stream>>>(
        t_p, z, ctx, eps, b_out, os_p, ws, out);
}